// Round 4
// baseline (564.282 us; speedup 1.0000x reference)
//
#include <hip/hip_runtime.h>
#include <hip/hip_fp16.h>

// QNetGNN: 2-layer GCN, N=100000, E=3.2M, F: 128 -> 16 -> 32.
// R14: front-end rewrite. R12's ablation shows the sort-based front-end
// (k_coarse/k_bin/k_csr: LDS counting sorts, 18-barrier scans, 2x full-edge
// LDS atomic passes) costs ~160 us of the 240; the gathers are small and
// latency-insensitive (R13: halving request width = neutral, since the TA
// already merged quad accesses). Replace with global-atomic CSR build:
//   k_deg    : deg[dst]++ (3.2M no-return global atomics, ~10us)
//   k_bsum   : per-256-node-bucket degree sums
//   k_scan   : exclusive scan of 392 bucket sums
//   k_rowptr : bucket-local scan -> rowptr/cursor/dis (+sentinel rowptr[n])
//   k_place  : pos = atomicAdd(&cursor[dst]); csr[pos] = src
// Gather keeps the R13 16-lane/node shape with scalar csr reads (unpadded
// rows); featp = fp16(x@W1 * dis) pre-scaled, W2/bias fused in layer 2.

#define NNODES 100000
#define FIN    128
#define FHID   16
#define NACT   32
#define NB     392          // ceil(100000/256) buckets of 256 nodes (scan tree)
#define BSH    8

__device__ __forceinline__ unsigned pack2(float a, float b) {
    __half2 h = __floats2half2_rn(a, b);
    return *reinterpret_cast<unsigned*>(&h);
}

__device__ __forceinline__ float2 h2f(unsigned u) {
    return __half22float2(*reinterpret_cast<__half2*>(&u));
}

// ---- deg[dst]++ over all edges ----
__global__ void k_deg(const int* __restrict__ dst, int E, int* __restrict__ deg) {
    int i = blockIdx.x * 256 + threadIdx.x;
    if (i < E) atomicAdd(&deg[dst[i]], 1);
}

// ---- per-bucket degree sums ----
__global__ void __launch_bounds__(256) k_bsum(const int* __restrict__ deg,
                                              int* __restrict__ bsum, int n) {
    __shared__ int part[256];
    int t = threadIdx.x;
    int node = (blockIdx.x << BSH) + t;
    part[t] = (node < n) ? deg[node] : 0;
    __syncthreads();
    for (int s = 128; s > 0; s >>= 1) {
        if (t < s) part[t] += part[t + s];
        __syncthreads();
    }
    if (t == 0) bsum[blockIdx.x] = part[0];
}

// ---- exclusive scan of bsum -> bptr[0..NB] (512 thr, NB<=512) ----
__global__ void __launch_bounds__(512) k_scan(
        const int* __restrict__ bcnt, int* __restrict__ bptr,
        int* __restrict__ gcur) {
    __shared__ int part[512];
    int t = threadIdx.x;
    int c = (t < NB) ? bcnt[t] : 0;
    part[t] = c;
    __syncthreads();
    for (int d = 1; d < 512; d <<= 1) {
        int v = part[t];
        int add = (t >= d) ? part[t - d] : 0;
        __syncthreads();
        part[t] = v + add;
        __syncthreads();
    }
    int excl = t ? part[t - 1] : 0;
    if (t < NB) { bptr[t] = excl; gcur[t] = excl; }
    if (t == NB) bptr[NB] = excl;      // total (c==0 for t>=NB)
}

// ---- bucket-local scan -> rowptr/cursor (+sentinel at node n), dis ----
__global__ void __launch_bounds__(256) k_rowptr(
        const int* __restrict__ deg, const int* __restrict__ bptr,
        int* __restrict__ rowptr, int* __restrict__ cursor,
        float* __restrict__ dis, int n) {
    __shared__ int part[256];
    int t = threadIdx.x;
    int bk = blockIdx.x;
    int node = (bk << BSH) + t;
    int d = (node < n) ? deg[node] : 0;
    part[t] = d;
    __syncthreads();
    for (int s = 1; s < 256; s <<= 1) {
        int v = part[t];
        int add = (t >= s) ? part[t - s] : 0;
        __syncthreads();
        part[t] = v + add;
        __syncthreads();
    }
    int excl = t ? part[t - 1] : 0;
    int rp = bptr[bk] + excl;
    if (node <= n) { rowptr[node] = rp; cursor[node] = rp; }   // node==n: sentinel=E
    if (node < n) dis[node] = rsqrtf((float)d + 1.0f);
}

// ---- scatter: csr[atomic cursor[dst]++] = src ----
__global__ void k_place(const int* __restrict__ src, const int* __restrict__ dst,
                        int E, int* __restrict__ cursor, int* __restrict__ csr) {
    int i = blockIdx.x * 256 + threadIdx.x;
    if (i < E) {
        int d = dst[i];
        int pos = atomicAdd(&cursor[d], 1);
        csr[pos] = src[i];
    }
}

#define FMA4(A, S, W) { (A).x += (S) * (W).x; (A).y += (S) * (W).y; \
                        (A).z += (S) * (W).z; (A).w += (S) * (W).w; }

// ---- featp = fp16((x @ W1) * dis); row n = zeros ----
__global__ void k_xw1(const float* __restrict__ x, const float* __restrict__ W1,
                      const float* __restrict__ dis, __half* __restrict__ featp, int n) {
    __shared__ float w[FIN * FHID];   // 8 KB, row-major [128][16]
    for (int i = threadIdx.x; i < FIN * FHID; i += blockDim.x) w[i] = W1[i];
    __syncthreads();
    int r = blockIdx.x * blockDim.x + threadIdx.x;
    if (r > n) return;
    uint4* hr = (uint4*)(featp + (size_t)r * FHID);   // 32 B row = 2 uint4
    if (r == n) {
        uint4 z = make_uint4(0u, 0u, 0u, 0u);
        hr[0] = z; hr[1] = z;
        return;
    }
    const float4* xr = (const float4*)(x + (long long)r * FIN);
    const float4* w4 = (const float4*)w;      // [128][4] float4s
    float4 a0 = make_float4(0.f, 0.f, 0.f, 0.f), a1 = a0, a2 = a0, a3 = a0;
#pragma unroll 8
    for (int k4 = 0; k4 < FIN / 4; ++k4) {
        float4 xv = xr[k4];
        int kb = k4 * 16;
        FMA4(a0, xv.x, w4[kb + 0]);  FMA4(a1, xv.x, w4[kb + 1]);
        FMA4(a2, xv.x, w4[kb + 2]);  FMA4(a3, xv.x, w4[kb + 3]);
        FMA4(a0, xv.y, w4[kb + 4]);  FMA4(a1, xv.y, w4[kb + 5]);
        FMA4(a2, xv.y, w4[kb + 6]);  FMA4(a3, xv.y, w4[kb + 7]);
        FMA4(a0, xv.z, w4[kb + 8]);  FMA4(a1, xv.z, w4[kb + 9]);
        FMA4(a2, xv.z, w4[kb + 10]); FMA4(a3, xv.z, w4[kb + 11]);
        FMA4(a0, xv.w, w4[kb + 12]); FMA4(a1, xv.w, w4[kb + 13]);
        FMA4(a2, xv.w, w4[kb + 14]); FMA4(a3, xv.w, w4[kb + 15]);
    }
    float d = dis[r];
    uint4 w0, w1;
    w0.x = pack2(a0.x * d, a0.y * d); w0.y = pack2(a0.z * d, a0.w * d);
    w0.z = pack2(a1.x * d, a1.y * d); w0.w = pack2(a1.z * d, a1.w * d);
    w1.x = pack2(a2.x * d, a2.y * d); w1.y = pack2(a2.z * d, a2.w * d);
    w1.z = pack2(a3.x * d, a3.y * d); w1.w = pack2(a3.z * d, a3.w * d);
    hr[0] = w0; hr[1] = w1;
}

// accumulate 8 fp16 (one uint4 = 16B half-row) into a0/a1
#define ACC8F(U) { float2 f_; \
    f_ = h2f((U).x); a0.x += f_.x; a0.y += f_.y; \
    f_ = h2f((U).y); a0.z += f_.x; a0.w += f_.y; \
    f_ = h2f((U).z); a1.x += f_.x; a1.y += f_.y; \
    f_ = h2f((U).w); a1.z += f_.x; a1.w += f_.y; }

// ---- gather: 16 lanes/node, uint4 (16B) feature loads, scalar csr reads ----
// lane l = t&15: p = l&1 selects 16B half-row, grp = l>>1 (8 groups) splits
// the (unpadded) csr row; lane pairs read the same csr int (broadcast).
// L==1: h1p = fp16(relu(di*sum + b1)*di)   [N,16]
// L==2: out = (di*sum) @ W2 + b2           [N,32] fp32 (W2 fused)
template <int L>
__global__ void __launch_bounds__(256, 6) k_gather(
        const int* __restrict__ rowptr, const int* __restrict__ csr,
        const float* __restrict__ dis, const __half* __restrict__ featp,
        const float* __restrict__ W2, const float* __restrict__ bias,
        void* __restrict__ outp, int n) {
    __shared__ float wb[FHID * NACT];
    __shared__ float bs[NACT];
    if (L == 2) {
        for (int i = threadIdx.x; i < FHID * NACT; i += 256) wb[i] = W2[i];
        if (threadIdx.x < NACT) bs[threadIdx.x] = bias[threadIdx.x];
        __syncthreads();
    }
    int t = blockIdx.x * blockDim.x + threadIdx.x;
    int node = t >> 4, l = t & 15, p = l & 1, grp = l >> 1;
    if (node > n) return;
    const uint4* fp4 = (const uint4*)featp;   // 2 uint4 (16B halves) per row
    if (node == n) {
        if (L == 1 && l < 2) ((uint4*)outp)[(size_t)node * 2 + p] = make_uint4(0u, 0u, 0u, 0u);
        return;
    }
    float4 a0 = make_float4(0.f, 0.f, 0.f, 0.f), a1 = a0;
    if (grp == 7) {   // self loop (pre-scaled)
        uint4 u = fp4[((size_t)node << 1) + p];
        ACC8F(u);
    }
    int beg = rowptr[node];
    int len = rowptr[node + 1] - beg;
    const int* cp = csr + beg;
    int k = grp;
    for (; k + 8 < len; k += 16) {            // 2 rows in flight per lane
        int s0 = cp[k];
        int s1 = cp[k + 8];
        uint4 u0 = fp4[(size_t)s0 * 2 + p];
        uint4 u1 = fp4[(size_t)s1 * 2 + p];
        ACC8F(u0); ACC8F(u1);
    }
    if (k < len) {
        int s0 = cp[k];
        uint4 u0 = fp4[(size_t)s0 * 2 + p];
        ACC8F(u0);
    }
    // reduce over grp bits (lane^2, lane^4, lane^8): all 16 lanes end with
    // the full sum for their half-row p
#pragma unroll
    for (int m = 2; m <= 8; m <<= 1) {
        a0.x += __shfl_xor(a0.x, m, 64);
        a0.y += __shfl_xor(a0.y, m, 64);
        a0.z += __shfl_xor(a0.z, m, 64);
        a0.w += __shfl_xor(a0.w, m, 64);
        a1.x += __shfl_xor(a1.x, m, 64);
        a1.y += __shfl_xor(a1.y, m, 64);
        a1.z += __shfl_xor(a1.z, m, 64);
        a1.w += __shfl_xor(a1.w, m, 64);
    }
    float di = dis[node];
    if (L == 1) {
        if (l < 2) {    // 2 lanes write the 2 x 16B halves of the fp16 row
            const float4* b4 = (const float4*)bias;
            float4 bv0 = b4[p * 2], bv1 = b4[p * 2 + 1];
            float r0 = fmaxf(di * a0.x + bv0.x, 0.f) * di;   // pre-scaled for layer 2
            float r1 = fmaxf(di * a0.y + bv0.y, 0.f) * di;
            float r2 = fmaxf(di * a0.z + bv0.z, 0.f) * di;
            float r3 = fmaxf(di * a0.w + bv0.w, 0.f) * di;
            float r4 = fmaxf(di * a1.x + bv1.x, 0.f) * di;
            float r5 = fmaxf(di * a1.y + bv1.y, 0.f) * di;
            float r6 = fmaxf(di * a1.z + bv1.z, 0.f) * di;
            float r7 = fmaxf(di * a1.w + bv1.w, 0.f) * di;
            uint4 w;
            w.x = pack2(r0, r1); w.y = pack2(r2, r3);
            w.z = pack2(r4, r5); w.w = pack2(r6, r7);
            ((uint4*)outp)[(size_t)node * 2 + p] = w;
        }
    } else {
        // gather the full 16-float hidden row (scaled by di) via shfl
        int base16 = (threadIdx.x & 63) & ~15;
        float v0 = di * a0.x, v1 = di * a0.y, v2 = di * a0.z, v3 = di * a0.w;
        float v4 = di * a1.x, v5 = di * a1.y, v6 = di * a1.z, v7 = di * a1.w;
        float p16[16];
        p16[0]  = __shfl(v0, base16,     64); p16[8]  = __shfl(v0, base16 + 1, 64);
        p16[1]  = __shfl(v1, base16,     64); p16[9]  = __shfl(v1, base16 + 1, 64);
        p16[2]  = __shfl(v2, base16,     64); p16[10] = __shfl(v2, base16 + 1, 64);
        p16[3]  = __shfl(v3, base16,     64); p16[11] = __shfl(v3, base16 + 1, 64);
        p16[4]  = __shfl(v4, base16,     64); p16[12] = __shfl(v4, base16 + 1, 64);
        p16[5]  = __shfl(v5, base16,     64); p16[13] = __shfl(v5, base16 + 1, 64);
        p16[6]  = __shfl(v6, base16,     64); p16[14] = __shfl(v6, base16 + 1, 64);
        p16[7]  = __shfl(v7, base16,     64); p16[15] = __shfl(v7, base16 + 1, 64);
        int col = l * 2;                 // each lane computes 2 of 32 columns
        float s0 = bs[col], s1 = bs[col + 1];
#pragma unroll
        for (int c = 0; c < FHID; ++c) {
            s0 += p16[c] * wb[c * NACT + col];
            s1 += p16[c] * wb[c * NACT + col + 1];
        }
        ((float2*)outp)[(size_t)node * 16 + l] = make_float2(s0, s1);
    }
}

extern "C" void kernel_launch(void* const* d_in, const int* in_sizes, int n_in,
                              void* d_out, int out_size, void* d_ws, size_t ws_size,
                              hipStream_t stream) {
    const float* x  = (const float*)d_in[0];
    const float* W1 = (const float*)d_in[1];
    const float* b1 = (const float*)d_in[2];
    const float* W2 = (const float*)d_in[3];
    const float* b2 = (const float*)d_in[4];
    const int*   ei = (const int*)d_in[5];
    const int E = in_sizes[5] / 2;
    const int n = NNODES;
    const int npad = n + 8;               // keeps fp16 tables 16B-aligned
    const int* src = ei;
    const int* dst = ei + E;

    // floats: dis[n] | featp fp16 [16*npad] | h1p fp16 [16*npad]
    // ints:   deg[n] | bptr[NB+1] | rowptr[n+1] | cursor[n+1] | bsum[NB] | csr[E]
    float* fb    = (float*)d_ws;
    float* dis   = fb;
    __half* featp = (__half*)(fb + (size_t)n);
    __half* h1p   = featp + (size_t)16 * npad;
    int*   ib    = (int*)(h1p + (size_t)16 * npad);
    int*   deg    = ib;
    int*   bptr   = deg + n;
    int*   rowptr = bptr + NB + 1;
    int*   cursor = rowptr + n + 1;
    int*   bsum   = cursor + n + 1;
    int*   csr    = bsum + NB;

    (void)hipMemsetAsync(deg, 0, (size_t)n * sizeof(int), stream);

    const int B = 256;
    const int EB = (E + B - 1) / B;
    k_deg<<<EB, B, 0, stream>>>(dst, E, deg);
    k_bsum<<<NB, B, 0, stream>>>(deg, bsum, n);
    k_scan<<<1, 512, 0, stream>>>(bsum, bptr, bsum);
    k_rowptr<<<NB, B, 0, stream>>>(deg, bptr, rowptr, cursor, dis, n);
    k_place<<<EB, B, 0, stream>>>(src, dst, E, cursor, csr);
    k_xw1<<<(n + 1 + B - 1) / B, B, 0, stream>>>(x, W1, dis, featp, n);
    k_gather<1><<<((n + 1) * 16 + B - 1) / B, B, 0, stream>>>(rowptr, csr, dis, featp,
                                                              nullptr, b1, (void*)h1p, n);
    k_gather<2><<<((n + 1) * 16 + B - 1) / B, B, 0, stream>>>(rowptr, csr, dis, h1p,
                                                              W2, b2, d_out, n);
}

// Round 5
// 234.543 us; speedup vs baseline: 2.4059x; 2.4059x over previous
//
#include <hip/hip_runtime.h>
#include <hip/hip_fp16.h>

// QNetGNN: 2-layer GCN, N=100000, E=3.2M, F: 128 -> 16 -> 32.
// R15: push aggregation, take 2. R12's push structure was right but used
// fp32 LDS atomicAdd (= ds_cmpst CAS retry loop -> 269us/layer). R14's
// global-atomic CSR build was worse (k_place 270us: returning device
// atomics + 64B-line write amplification, WRITE_SIZE 194MB measured).
// Fix: accumulate FIXED-POINT INT32 in LDS (scale 2^18). Int atomicAdd
// with unused return is native ds_add_u32 (fire-and-forget; precedent:
// k_coarse's 3.2M LDS hist atomics run inside the fast front-end).
// Front-end (k_coarse/k_scan/k_bin, NB=511, BUCK=196, magic division)
// is verbatim from R12 which PASSED correctness on HW. k_csr and the
// pull gathers are gone; no CSR, no padding, no dependent load chains.
// featp = fp16(x@W1 * dis) pre-scaled by source norm; h1p likewise.

#define NNODES 100000
#define FIN    128
#define FHID   16
#define NACT   32
#define BUCK   196          // nodes per bucket (511 blocks ~= 2/CU balance)
#define NB     511          // ceil(100000/196)
#define MAGIC  21913099u    // ceil(2^32/196); exact for d < 39.7M (R12-verified)
#define TILE   4096
#define ASTRIDE 17          // LDS accumulator row stride (odd -> bank spread)
#define SCALE    262144.0f             // 2^18 fixed-point scale
#define INVSCALE 3.814697265625e-06f   // 2^-18

__device__ __forceinline__ int bucket_of(int d) {
    return (int)__umulhi((unsigned)d, MAGIC);
}

__device__ __forceinline__ unsigned pack2(float a, float b) {
    __half2 h = __floats2half2_rn(a, b);
    return *reinterpret_cast<unsigned*>(&h);
}

__device__ __forceinline__ float2 h2f(unsigned u) {
    return __half22float2(*reinterpret_cast<__half2*>(&u));
}

// ---- coarse histogram of dst buckets; also store per-tile hist (ushort) ----
__global__ void k_coarse(const int* __restrict__ dst, int E, int* __restrict__ bcnt,
                         unsigned short* __restrict__ thist) {
    __shared__ int hist[NB];
    int t = threadIdx.x;
    int tb = blockIdx.x * TILE;
    int tn = min(TILE, E - tb);
    for (int i = t; i < NB; i += 256) hist[i] = 0;
    __syncthreads();
    for (int i = t; i < tn; i += 256) atomicAdd(&hist[bucket_of(dst[tb + i])], 1);
    __syncthreads();
    size_t row = (size_t)blockIdx.x * NB;
    for (int i = t; i < NB; i += 256) {
        int hv = hist[i];
        thist[row + i] = (unsigned short)hv;
        if (hv) atomicAdd(&bcnt[i], hv);
    }
}

// ---- exclusive scan of bcnt -> bptr[0..NB], init gcur (512 thr, NB<=512) ----
__global__ void __launch_bounds__(512) k_scan(
        const int* __restrict__ bcnt, int* __restrict__ bptr,
        int* __restrict__ gcur) {
    __shared__ int part[512];
    int t = threadIdx.x;
    int c = (t < NB) ? bcnt[t] : 0;
    part[t] = c;
    __syncthreads();
    for (int d = 1; d < 512; d <<= 1) {
        int v = part[t];
        int add = (t >= d) ? part[t - d] : 0;
        __syncthreads();
        part[t] = v + add;
        __syncthreads();
    }
    int excl = t ? part[t - 1] : 0;
    if (t < NB) { bptr[t] = excl; gcur[t] = excl; }
    if (t == NB) bptr[NB] = excl;      // total (c==0 for t>=NB)
}

// ---- bin: staged LDS counting sort, precomputed global dests, 512 thr ----
__global__ void __launch_bounds__(512) k_bin(
        const int* __restrict__ src, const int* __restrict__ dst, int E,
        int* __restrict__ gcur, const unsigned short* __restrict__ thist,
        unsigned* __restrict__ binned) {
    __shared__ unsigned staged[TILE];     // 16 KB
    __shared__ int gscat[TILE];           // 16 KB
    __shared__ int lstart[NB + 1];
    __shared__ int lcur[NB];
    __shared__ int gbase[NB];
    __shared__ int part[512];
    int t = threadIdx.x;
    int tb = blockIdx.x * TILE;
    int tn = min(TILE, E - tb);
    size_t row = (size_t)blockIdx.x * NB;
    int c = (t < NB) ? (int)thist[row + t] : 0;
    part[t] = c;
    __syncthreads();
    for (int d = 1; d < 512; d <<= 1) {
        int v = part[t];
        int add = (t >= d) ? part[t - d] : 0;
        __syncthreads();
        part[t] = v + add;
        __syncthreads();
    }
    int excl = t ? part[t - 1] : 0;
    if (t < NB) { lstart[t] = excl; lcur[t] = excl; }
    if (t == NB) lstart[NB] = excl;
    __syncthreads();
    if (t < NB) gbase[t] = (c > 0) ? atomicAdd(&gcur[t], c) : 0;
    __syncthreads();
    for (int i = t; i < tn; i += 512) {
        int d = dst[tb + i], sv = src[tb + i];
        int b = bucket_of(d);
        int pos = atomicAdd(&lcur[b], 1);
        staged[pos] = ((unsigned)sv << 8) | (unsigned)(d - b * BUCK);
        gscat[pos] = gbase[b] + (pos - lstart[b]);
    }
    __syncthreads();
    for (int j = t; j < tn; j += 512) binned[gscat[j]] = staged[j];
}

// ---- per-bucket degree count -> dis (needed before k_xw1 pre-scaling) ----
__global__ void k_deg(const int* __restrict__ bptr, const unsigned* __restrict__ binned,
                      float* __restrict__ dis, int n) {
    __shared__ int cnt[BUCK];
    int t = threadIdx.x;
    int bk = blockIdx.x;
    if (t < BUCK) cnt[t] = 0;
    __syncthreads();
    int beg = bptr[bk], end = bptr[bk + 1];
    for (int i = beg + t; i < end; i += 256) atomicAdd(&cnt[binned[i] & 255], 1);
    __syncthreads();
    int node = bk * BUCK + t;
    if (t < BUCK && node < n) dis[node] = rsqrtf((float)cnt[t] + 1.0f);
}

#define FMA4(A, S, W) { (A).x += (S) * (W).x; (A).y += (S) * (W).y; \
                        (A).z += (S) * (W).z; (A).w += (S) * (W).w; }

// ---- featp = fp16((x @ W1) * dis); row n = zeros ----
__global__ void k_xw1(const float* __restrict__ x, const float* __restrict__ W1,
                      const float* __restrict__ dis, __half* __restrict__ featp, int n) {
    __shared__ float w[FIN * FHID];   // 8 KB, row-major [128][16]
    for (int i = threadIdx.x; i < FIN * FHID; i += blockDim.x) w[i] = W1[i];
    __syncthreads();
    int r = blockIdx.x * blockDim.x + threadIdx.x;
    if (r > n) return;
    uint4* hr = (uint4*)(featp + (size_t)r * FHID);   // 32 B row = 2 uint4
    if (r == n) {
        uint4 z = make_uint4(0u, 0u, 0u, 0u);
        hr[0] = z; hr[1] = z;
        return;
    }
    const float4* xr = (const float4*)(x + (long long)r * FIN);
    const float4* w4 = (const float4*)w;      // [128][4] float4s
    float4 a0 = make_float4(0.f, 0.f, 0.f, 0.f), a1 = a0, a2 = a0, a3 = a0;
#pragma unroll 8
    for (int k4 = 0; k4 < FIN / 4; ++k4) {
        float4 xv = xr[k4];
        int kb = k4 * 16;
        FMA4(a0, xv.x, w4[kb + 0]);  FMA4(a1, xv.x, w4[kb + 1]);
        FMA4(a2, xv.x, w4[kb + 2]);  FMA4(a3, xv.x, w4[kb + 3]);
        FMA4(a0, xv.y, w4[kb + 4]);  FMA4(a1, xv.y, w4[kb + 5]);
        FMA4(a2, xv.y, w4[kb + 6]);  FMA4(a3, xv.y, w4[kb + 7]);
        FMA4(a0, xv.z, w4[kb + 8]);  FMA4(a1, xv.z, w4[kb + 9]);
        FMA4(a2, xv.z, w4[kb + 10]); FMA4(a3, xv.z, w4[kb + 11]);
        FMA4(a0, xv.w, w4[kb + 12]); FMA4(a1, xv.w, w4[kb + 13]);
        FMA4(a2, xv.w, w4[kb + 14]); FMA4(a3, xv.w, w4[kb + 15]);
    }
    float d = dis[r];
    uint4 w0, w1;
    w0.x = pack2(a0.x * d, a0.y * d); w0.y = pack2(a0.z * d, a0.w * d);
    w0.z = pack2(a1.x * d, a1.y * d); w0.w = pack2(a1.z * d, a1.w * d);
    w1.x = pack2(a2.x * d, a2.y * d); w1.y = pack2(a2.z * d, a2.w * d);
    w1.z = pack2(a3.x * d, a3.y * d); w1.w = pack2(a3.z * d, a3.w * d);
    hr[0] = w0; hr[1] = w1;
}

// ---- push aggregation: block per bucket, int32 fixed-point LDS acc ----
// Per edge: a quad of lanes reads the 32B source row (2x uint2 granules
// per... 1 uint2/lane), converts to fixed-point, 4x ds_add_u32 each.
// L==1: h1p = fp16(relu(di*acc + b1)*di)   [N,16]
// L==2: out = (di*acc) @ W2 + b2           [N,32] fp32 (W2 fused)
template <int L>
__global__ void __launch_bounds__(512) k_agg(
        const int* __restrict__ bptr, const unsigned* __restrict__ binned,
        const float* __restrict__ dis, const __half* __restrict__ featp,
        const float* __restrict__ W2, const float* __restrict__ bias,
        void* __restrict__ outp, int n) {
    __shared__ int acc[BUCK * ASTRIDE];      // 13.3 KB
    __shared__ float wb[FHID * NACT];
    __shared__ float bs[NACT];
    int t = threadIdx.x;
    int bk = blockIdx.x;
    int base = bk * BUCK;
    int nn = min(BUCK, n - base);
    const uint2* fp = (const uint2*)featp;   // 4 granules of 8 B per row
    if (L == 2) {
        for (int i = t; i < FHID * NACT; i += 512) wb[i] = W2[i];
        if (t < NACT) bs[t] = bias[t];
    }
    // init acc with the self-loop row (featp pre-scaled by dis[node])
    for (int idx = t; idx < BUCK * 4; idx += 512) {
        int d = idx >> 2, p = idx & 3;
        int4 v = make_int4(0, 0, 0, 0);
        if (d < nn) {
            uint2 u = fp[(size_t)((base + d) << 2) + p];
            float2 f0 = h2f(u.x), f1 = h2f(u.y);
            v.x = __float2int_rn(f0.x * SCALE);
            v.y = __float2int_rn(f0.y * SCALE);
            v.z = __float2int_rn(f1.x * SCALE);
            v.w = __float2int_rn(f1.y * SCALE);
        }
        int* a = &acc[d * ASTRIDE + p * 4];
        a[0] = v.x; a[1] = v.y; a[2] = v.z; a[3] = v.w;
    }
    __syncthreads();
    int beg = bptr[bk], end = bptr[bk + 1];
    int q = t >> 2, p = t & 3;               // quad of lanes per edge
    int i = beg + q;
    for (; i + 128 < end; i += 256) {        // 2 edges in flight per quad
        unsigned e0 = binned[i];
        unsigned e1 = binned[i + 128];
        uint2 u0 = fp[(size_t)((e0 >> 8) << 2) + p];
        uint2 u1 = fp[(size_t)((e1 >> 8) << 2) + p];
        float2 a0 = h2f(u0.x), b0 = h2f(u0.y);
        float2 a1 = h2f(u1.x), b1v = h2f(u1.y);
        int* d0 = &acc[(int)(e0 & 255) * ASTRIDE + p * 4];
        atomicAdd(&d0[0], __float2int_rn(a0.x * SCALE));
        atomicAdd(&d0[1], __float2int_rn(a0.y * SCALE));
        atomicAdd(&d0[2], __float2int_rn(b0.x * SCALE));
        atomicAdd(&d0[3], __float2int_rn(b0.y * SCALE));
        int* d1 = &acc[(int)(e1 & 255) * ASTRIDE + p * 4];
        atomicAdd(&d1[0], __float2int_rn(a1.x * SCALE));
        atomicAdd(&d1[1], __float2int_rn(a1.y * SCALE));
        atomicAdd(&d1[2], __float2int_rn(b1v.x * SCALE));
        atomicAdd(&d1[3], __float2int_rn(b1v.y * SCALE));
    }
    if (i < end) {
        unsigned e0 = binned[i];
        uint2 u0 = fp[(size_t)((e0 >> 8) << 2) + p];
        float2 a0 = h2f(u0.x), b0 = h2f(u0.y);
        int* d0 = &acc[(int)(e0 & 255) * ASTRIDE + p * 4];
        atomicAdd(&d0[0], __float2int_rn(a0.x * SCALE));
        atomicAdd(&d0[1], __float2int_rn(a0.y * SCALE));
        atomicAdd(&d0[2], __float2int_rn(b0.x * SCALE));
        atomicAdd(&d0[3], __float2int_rn(b0.y * SCALE));
    }
    __syncthreads();
    if (L == 1) {
        for (int idx = t; idx < nn * 4; idx += 512) {
            int d = idx >> 2, pp = idx & 3;
            int node = base + d;
            float di = dis[node];
            const int* a = &acc[d * ASTRIDE + pp * 4];
            float4 bv = ((const float4*)bias)[pp];
            float f0 = (float)a[0] * INVSCALE;
            float f1 = (float)a[1] * INVSCALE;
            float f2 = (float)a[2] * INVSCALE;
            float f3 = (float)a[3] * INVSCALE;
            float rx = fmaxf(di * f0 + bv.x, 0.f) * di;   // pre-scaled for layer 2
            float ry = fmaxf(di * f1 + bv.y, 0.f) * di;
            float rz = fmaxf(di * f2 + bv.z, 0.f) * di;
            float rw = fmaxf(di * f3 + bv.w, 0.f) * di;
            uint2 w;
            w.x = pack2(rx, ry);
            w.y = pack2(rz, rw);
            ((uint2*)outp)[(size_t)node * 4 + pp] = w;
        }
    } else {
        for (int idx = t; idx < nn * 2; idx += 512) {
            int d = idx >> 1, h = idx & 1;   // 2 threads/node, 16 cols each
            int node = base + d;
            float di = dis[node];
            float p16[FHID];
#pragma unroll
            for (int c = 0; c < FHID; ++c)
                p16[c] = di * ((float)acc[d * ASTRIDE + c] * INVSCALE);
            float o[16];
#pragma unroll
            for (int j = 0; j < 16; ++j) {
                int col = h * 16 + j;
                float s = bs[col];
#pragma unroll
                for (int c = 0; c < FHID; ++c) s += p16[c] * wb[c * NACT + col];
                o[j] = s;
            }
            float4* orow = (float4*)outp + (size_t)node * 8 + h * 4;
            orow[0] = make_float4(o[0], o[1], o[2], o[3]);
            orow[1] = make_float4(o[4], o[5], o[6], o[7]);
            orow[2] = make_float4(o[8], o[9], o[10], o[11]);
            orow[3] = make_float4(o[12], o[13], o[14], o[15]);
        }
    }
}

extern "C" void kernel_launch(void* const* d_in, const int* in_sizes, int n_in,
                              void* d_out, int out_size, void* d_ws, size_t ws_size,
                              hipStream_t stream) {
    const float* x  = (const float*)d_in[0];
    const float* W1 = (const float*)d_in[1];
    const float* b1 = (const float*)d_in[2];
    const float* W2 = (const float*)d_in[3];
    const float* b2 = (const float*)d_in[4];
    const int*   ei = (const int*)d_in[5];
    const int E = in_sizes[5] / 2;
    const int n = NNODES;
    const int npad = n + 8;               // keeps fp16 tables 16B-aligned
    const int* src = ei;
    const int* dst = ei + E;
    const int ntiles = (E + TILE - 1) / TILE;

    // floats: dis[n] | featp fp16 [16*npad] | h1p fp16 [16*npad]
    // ints:   bcnt[NB] bptr[NB+1] gcur[NB] | thist[ntiles*NB] ushort | binned[E]
    float* fb    = (float*)d_ws;
    float* dis   = fb;
    __half* featp = (__half*)(fb + (size_t)n);
    __half* h1p   = featp + (size_t)16 * npad;
    int*   ib    = (int*)(h1p + (size_t)16 * npad);
    int*   bcnt  = ib;
    int*   bptr  = ib + NB;
    int*   gcur  = ib + 2 * NB + 1;
    size_t thist_off = (size_t)(3 * NB + 1);
    unsigned short* thist = (unsigned short*)(ib + thist_off);
    size_t thist_ints = ((size_t)ntiles * NB + 1) / 2;
    unsigned* binned = (unsigned*)(ib + thist_off + thist_ints);

    (void)hipMemsetAsync(bcnt, 0, NB * sizeof(int), stream);

    const int B = 256;
    k_coarse<<<ntiles, B, 0, stream>>>(dst, E, bcnt, thist);
    k_scan<<<1, 512, 0, stream>>>(bcnt, bptr, gcur);
    k_bin<<<ntiles, 512, 0, stream>>>(src, dst, E, gcur, thist, binned);
    k_deg<<<NB, B, 0, stream>>>(bptr, binned, dis, n);
    k_xw1<<<(n + 1 + B - 1) / B, B, 0, stream>>>(x, W1, dis, featp, n);
    k_agg<1><<<NB, 512, 0, stream>>>(bptr, binned, dis, featp, nullptr, b1, (void*)h1p, n);
    k_agg<2><<<NB, 512, 0, stream>>>(bptr, binned, dis, h1p, W2, b2, d_out, n);
}

// Round 6
// 230.050 us; speedup vs baseline: 2.4529x; 1.0195x over previous
//
#include <hip/hip_runtime.h>
#include <hip/hip_fp16.h>

// QNetGNN: 2-layer GCN, N=100000, E=3.2M, F: 128 -> 16 -> 32.
// R16: k_bin de-serialization. R15 (fixed-point int LDS atomics in k_agg)
// passed at 234.5us; only k_bin (41.3us) remains above the profiling
// cutoff, with VALUBusy 3.6% / HBM 12% -> barrier/serialization bound.
// Changes:
//  - shfl-based scans (1 barrier) replace the 18-barrier ladder scans.
//  - k_scan kernel DELETED: each k_bin block recomputes the bcnt scan
//    itself (cheap with shfl); block 0 publishes bptr; gcur is zero-based
//    and covered by the bcnt memset.
//  - sort-loop scatter index via dbase[b] = bptrS[b] + gbase - lstart[b].
// Everything else verbatim from R15 (front-end NB=511/BUCK=196 magic
// division, fixed-point 2^18 LDS accumulation, fused W2 epilogue).

#define NNODES 100000
#define FIN    128
#define FHID   16
#define NACT   32
#define BUCK   196          // nodes per bucket (511 blocks ~= 2/CU balance)
#define NB     511          // ceil(100000/196)
#define MAGIC  21913099u    // ceil(2^32/196); exact for d < 39.7M (R12-verified)
#define TILE   4096
#define ASTRIDE 17          // LDS accumulator row stride (odd -> bank spread)
#define SCALE    262144.0f             // 2^18 fixed-point scale
#define INVSCALE 3.814697265625e-06f   // 2^-18

__device__ __forceinline__ int bucket_of(int d) {
    return (int)__umulhi((unsigned)d, MAGIC);
}

__device__ __forceinline__ unsigned pack2(float a, float b) {
    __half2 h = __floats2half2_rn(a, b);
    return *reinterpret_cast<unsigned*>(&h);
}

__device__ __forceinline__ float2 h2f(unsigned u) {
    return __half22float2(*reinterpret_cast<__half2*>(&u));
}

__device__ __forceinline__ int wave_iscan(int v, int lane) {
#pragma unroll
    for (int d = 1; d < 64; d <<= 1) {
        int u = __shfl_up(v, d, 64);
        if (lane >= d) v += u;
    }
    return v;
}

// ---- coarse histogram of dst buckets; also store per-tile hist (ushort) ----
__global__ void k_coarse(const int* __restrict__ dst, int E, int* __restrict__ bcnt,
                         unsigned short* __restrict__ thist) {
    __shared__ int hist[NB];
    int t = threadIdx.x;
    int tb = blockIdx.x * TILE;
    int tn = min(TILE, E - tb);
    for (int i = t; i < NB; i += 256) hist[i] = 0;
    __syncthreads();
    for (int i = t; i < tn; i += 256) atomicAdd(&hist[bucket_of(dst[tb + i])], 1);
    __syncthreads();
    size_t row = (size_t)blockIdx.x * NB;
    for (int i = t; i < NB; i += 256) {
        int hv = hist[i];
        thist[row + i] = (unsigned short)hv;
        if (hv) atomicAdd(&bcnt[i], hv);
    }
}

// ---- bin: staged LDS counting sort; shfl scans; k_scan folded in ----
__global__ void __launch_bounds__(512) k_bin(
        const int* __restrict__ src, const int* __restrict__ dst, int E,
        const int* __restrict__ bcnt, int* __restrict__ gcur,
        const unsigned short* __restrict__ thist,
        int* __restrict__ bptr, unsigned* __restrict__ binned) {
    __shared__ unsigned staged[TILE];     // 16 KB
    __shared__ int gscat[TILE];           // 16 KB
    __shared__ int lcur[NB];
    __shared__ int dbase[NB];
    __shared__ int bptrS[NB];
    __shared__ int wsum[8];
    int t = threadIdx.x, lane = t & 63, wv = t >> 6;

    // --- block-wide exclusive scan of bcnt -> bptrS (shfl, 1 barrier) ---
    int c0 = (t < NB) ? bcnt[t] : 0;
    int incl0 = wave_iscan(c0, lane);
    if (lane == 63) wsum[wv] = incl0;
    __syncthreads();
    int add0 = 0;
#pragma unroll
    for (int i = 0; i < 8; ++i) add0 += (i < wv) ? wsum[i] : 0;
    incl0 += add0;
    int excl0 = incl0 - c0;
    if (t < NB) bptrS[t] = excl0;
    if (blockIdx.x == 0) {                // publish bptr for k_deg/k_agg
        if (t < NB) bptr[t] = excl0;
        if (t == NB) bptr[NB] = excl0;    // t==NB: c0=0 -> excl0 = total E
    }
    __syncthreads();                      // wsum reuse + bptrS visibility

    // --- per-tile local scan of thist row (shfl, 1 barrier) ---
    int tb = blockIdx.x * TILE;
    int tn = min(TILE, E - tb);
    size_t row = (size_t)blockIdx.x * NB;
    int c = (t < NB) ? (int)thist[row + t] : 0;
    int incl = wave_iscan(c, lane);
    if (lane == 63) wsum[wv] = incl;
    __syncthreads();
    int add = 0;
#pragma unroll
    for (int i = 0; i < 8; ++i) add += (i < wv) ? wsum[i] : 0;
    incl += add;
    int excl = incl - c;                  // tile-local bucket start
    if (t < NB) {
        lcur[t] = excl;
        int gb = (c > 0) ? atomicAdd(&gcur[t], c) : 0;   // zero-based cursor
        dbase[t] = bptrS[t] + gb - excl;  // dest = dbase[b] + staged pos
    }
    __syncthreads();

    for (int i = t; i < tn; i += 512) {
        int d = dst[tb + i], sv = src[tb + i];
        int b = bucket_of(d);
        int pos = atomicAdd(&lcur[b], 1);
        staged[pos] = ((unsigned)sv << 8) | (unsigned)(d - b * BUCK);
        gscat[pos] = dbase[b] + pos;
    }
    __syncthreads();
    for (int j = t; j < tn; j += 512) binned[gscat[j]] = staged[j];
}

// ---- per-bucket degree count -> dis (needed before k_xw1 pre-scaling) ----
__global__ void k_deg(const int* __restrict__ bptr, const unsigned* __restrict__ binned,
                      float* __restrict__ dis, int n) {
    __shared__ int cnt[BUCK];
    int t = threadIdx.x;
    int bk = blockIdx.x;
    if (t < BUCK) cnt[t] = 0;
    __syncthreads();
    int beg = bptr[bk], end = bptr[bk + 1];
    for (int i = beg + t; i < end; i += 256) atomicAdd(&cnt[binned[i] & 255], 1);
    __syncthreads();
    int node = bk * BUCK + t;
    if (t < BUCK && node < n) dis[node] = rsqrtf((float)cnt[t] + 1.0f);
}

#define FMA4(A, S, W) { (A).x += (S) * (W).x; (A).y += (S) * (W).y; \
                        (A).z += (S) * (W).z; (A).w += (S) * (W).w; }

// ---- featp = fp16((x @ W1) * dis); row n = zeros ----
__global__ void k_xw1(const float* __restrict__ x, const float* __restrict__ W1,
                      const float* __restrict__ dis, __half* __restrict__ featp, int n) {
    __shared__ float w[FIN * FHID];   // 8 KB, row-major [128][16]
    for (int i = threadIdx.x; i < FIN * FHID; i += blockDim.x) w[i] = W1[i];
    __syncthreads();
    int r = blockIdx.x * blockDim.x + threadIdx.x;
    if (r > n) return;
    uint4* hr = (uint4*)(featp + (size_t)r * FHID);   // 32 B row = 2 uint4
    if (r == n) {
        uint4 z = make_uint4(0u, 0u, 0u, 0u);
        hr[0] = z; hr[1] = z;
        return;
    }
    const float4* xr = (const float4*)(x + (long long)r * FIN);
    const float4* w4 = (const float4*)w;      // [128][4] float4s
    float4 a0 = make_float4(0.f, 0.f, 0.f, 0.f), a1 = a0, a2 = a0, a3 = a0;
#pragma unroll 8
    for (int k4 = 0; k4 < FIN / 4; ++k4) {
        float4 xv = xr[k4];
        int kb = k4 * 16;
        FMA4(a0, xv.x, w4[kb + 0]);  FMA4(a1, xv.x, w4[kb + 1]);
        FMA4(a2, xv.x, w4[kb + 2]);  FMA4(a3, xv.x, w4[kb + 3]);
        FMA4(a0, xv.y, w4[kb + 4]);  FMA4(a1, xv.y, w4[kb + 5]);
        FMA4(a2, xv.y, w4[kb + 6]);  FMA4(a3, xv.y, w4[kb + 7]);
        FMA4(a0, xv.z, w4[kb + 8]);  FMA4(a1, xv.z, w4[kb + 9]);
        FMA4(a2, xv.z, w4[kb + 10]); FMA4(a3, xv.z, w4[kb + 11]);
        FMA4(a0, xv.w, w4[kb + 12]); FMA4(a1, xv.w, w4[kb + 13]);
        FMA4(a2, xv.w, w4[kb + 14]); FMA4(a3, xv.w, w4[kb + 15]);
    }
    float d = dis[r];
    uint4 w0, w1;
    w0.x = pack2(a0.x * d, a0.y * d); w0.y = pack2(a0.z * d, a0.w * d);
    w0.z = pack2(a1.x * d, a1.y * d); w0.w = pack2(a1.z * d, a1.w * d);
    w1.x = pack2(a2.x * d, a2.y * d); w1.y = pack2(a2.z * d, a2.w * d);
    w1.z = pack2(a3.x * d, a3.y * d); w1.w = pack2(a3.z * d, a3.w * d);
    hr[0] = w0; hr[1] = w1;
}

// ---- push aggregation: block per bucket, int32 fixed-point LDS acc ----
// L==1: h1p = fp16(relu(di*acc + b1)*di)   [N,16]
// L==2: out = (di*acc) @ W2 + b2           [N,32] fp32 (W2 fused)
template <int L>
__global__ void __launch_bounds__(512) k_agg(
        const int* __restrict__ bptr, const unsigned* __restrict__ binned,
        const float* __restrict__ dis, const __half* __restrict__ featp,
        const float* __restrict__ W2, const float* __restrict__ bias,
        void* __restrict__ outp, int n) {
    __shared__ int acc[BUCK * ASTRIDE];      // 13.3 KB
    __shared__ float wb[FHID * NACT];
    __shared__ float bs[NACT];
    int t = threadIdx.x;
    int bk = blockIdx.x;
    int base = bk * BUCK;
    int nn = min(BUCK, n - base);
    const uint2* fp = (const uint2*)featp;   // 4 granules of 8 B per row
    if (L == 2) {
        for (int i = t; i < FHID * NACT; i += 512) wb[i] = W2[i];
        if (t < NACT) bs[t] = bias[t];
    }
    // init acc with the self-loop row (featp pre-scaled by dis[node])
    for (int idx = t; idx < BUCK * 4; idx += 512) {
        int d = idx >> 2, p = idx & 3;
        int4 v = make_int4(0, 0, 0, 0);
        if (d < nn) {
            uint2 u = fp[(size_t)((base + d) << 2) + p];
            float2 f0 = h2f(u.x), f1 = h2f(u.y);
            v.x = __float2int_rn(f0.x * SCALE);
            v.y = __float2int_rn(f0.y * SCALE);
            v.z = __float2int_rn(f1.x * SCALE);
            v.w = __float2int_rn(f1.y * SCALE);
        }
        int* a = &acc[d * ASTRIDE + p * 4];
        a[0] = v.x; a[1] = v.y; a[2] = v.z; a[3] = v.w;
    }
    __syncthreads();
    int beg = bptr[bk], end = bptr[bk + 1];
    int q = t >> 2, p = t & 3;               // quad of lanes per edge
    int i = beg + q;
    for (; i + 128 < end; i += 256) {        // 2 edges in flight per quad
        unsigned e0 = binned[i];
        unsigned e1 = binned[i + 128];
        uint2 u0 = fp[(size_t)((e0 >> 8) << 2) + p];
        uint2 u1 = fp[(size_t)((e1 >> 8) << 2) + p];
        float2 a0 = h2f(u0.x), b0 = h2f(u0.y);
        float2 a1 = h2f(u1.x), b1v = h2f(u1.y);
        int* d0 = &acc[(int)(e0 & 255) * ASTRIDE + p * 4];
        atomicAdd(&d0[0], __float2int_rn(a0.x * SCALE));
        atomicAdd(&d0[1], __float2int_rn(a0.y * SCALE));
        atomicAdd(&d0[2], __float2int_rn(b0.x * SCALE));
        atomicAdd(&d0[3], __float2int_rn(b0.y * SCALE));
        int* d1 = &acc[(int)(e1 & 255) * ASTRIDE + p * 4];
        atomicAdd(&d1[0], __float2int_rn(a1.x * SCALE));
        atomicAdd(&d1[1], __float2int_rn(a1.y * SCALE));
        atomicAdd(&d1[2], __float2int_rn(b1v.x * SCALE));
        atomicAdd(&d1[3], __float2int_rn(b1v.y * SCALE));
    }
    if (i < end) {
        unsigned e0 = binned[i];
        uint2 u0 = fp[(size_t)((e0 >> 8) << 2) + p];
        float2 a0 = h2f(u0.x), b0 = h2f(u0.y);
        int* d0 = &acc[(int)(e0 & 255) * ASTRIDE + p * 4];
        atomicAdd(&d0[0], __float2int_rn(a0.x * SCALE));
        atomicAdd(&d0[1], __float2int_rn(a0.y * SCALE));
        atomicAdd(&d0[2], __float2int_rn(b0.x * SCALE));
        atomicAdd(&d0[3], __float2int_rn(b0.y * SCALE));
    }
    __syncthreads();
    if (L == 1) {
        for (int idx = t; idx < nn * 4; idx += 512) {
            int d = idx >> 2, pp = idx & 3;
            int node = base + d;
            float di = dis[node];
            const int* a = &acc[d * ASTRIDE + pp * 4];
            float4 bv = ((const float4*)bias)[pp];
            float f0 = (float)a[0] * INVSCALE;
            float f1 = (float)a[1] * INVSCALE;
            float f2 = (float)a[2] * INVSCALE;
            float f3 = (float)a[3] * INVSCALE;
            float rx = fmaxf(di * f0 + bv.x, 0.f) * di;   // pre-scaled for layer 2
            float ry = fmaxf(di * f1 + bv.y, 0.f) * di;
            float rz = fmaxf(di * f2 + bv.z, 0.f) * di;
            float rw = fmaxf(di * f3 + bv.w, 0.f) * di;
            uint2 w;
            w.x = pack2(rx, ry);
            w.y = pack2(rz, rw);
            ((uint2*)outp)[(size_t)node * 4 + pp] = w;
        }
    } else {
        for (int idx = t; idx < nn * 2; idx += 512) {
            int d = idx >> 1, h = idx & 1;   // 2 threads/node, 16 cols each
            int node = base + d;
            float di = dis[node];
            float p16[FHID];
#pragma unroll
            for (int c = 0; c < FHID; ++c)
                p16[c] = di * ((float)acc[d * ASTRIDE + c] * INVSCALE);
            float o[16];
#pragma unroll
            for (int j = 0; j < 16; ++j) {
                int col = h * 16 + j;
                float s = bs[col];
#pragma unroll
                for (int c = 0; c < FHID; ++c) s += p16[c] * wb[c * NACT + col];
                o[j] = s;
            }
            float4* orow = (float4*)outp + (size_t)node * 8 + h * 4;
            orow[0] = make_float4(o[0], o[1], o[2], o[3]);
            orow[1] = make_float4(o[4], o[5], o[6], o[7]);
            orow[2] = make_float4(o[8], o[9], o[10], o[11]);
            orow[3] = make_float4(o[12], o[13], o[14], o[15]);
        }
    }
}

extern "C" void kernel_launch(void* const* d_in, const int* in_sizes, int n_in,
                              void* d_out, int out_size, void* d_ws, size_t ws_size,
                              hipStream_t stream) {
    const float* x  = (const float*)d_in[0];
    const float* W1 = (const float*)d_in[1];
    const float* b1 = (const float*)d_in[2];
    const float* W2 = (const float*)d_in[3];
    const float* b2 = (const float*)d_in[4];
    const int*   ei = (const int*)d_in[5];
    const int E = in_sizes[5] / 2;
    const int n = NNODES;
    const int npad = n + 8;               // keeps fp16 tables 16B-aligned
    const int* src = ei;
    const int* dst = ei + E;
    const int ntiles = (E + TILE - 1) / TILE;

    // floats: dis[n] | featp fp16 [16*npad] | h1p fp16 [16*npad]
    // ints:   bcnt[NB] gcur[NB] bptr[NB+1] | thist[ntiles*NB] ushort | binned[E]
    float* fb    = (float*)d_ws;
    float* dis   = fb;
    __half* featp = (__half*)(fb + (size_t)n);
    __half* h1p   = featp + (size_t)16 * npad;
    int*   ib    = (int*)(h1p + (size_t)16 * npad);
    int*   bcnt  = ib;
    int*   gcur  = ib + NB;
    int*   bptr  = ib + 2 * NB;
    size_t thist_off = (size_t)(3 * NB + 1);
    unsigned short* thist = (unsigned short*)(ib + thist_off);
    size_t thist_ints = ((size_t)ntiles * NB + 1) / 2;
    unsigned* binned = (unsigned*)(ib + thist_off + thist_ints);

    (void)hipMemsetAsync(bcnt, 0, 2 * NB * sizeof(int), stream);   // bcnt + gcur

    const int B = 256;
    k_coarse<<<ntiles, B, 0, stream>>>(dst, E, bcnt, thist);
    k_bin<<<ntiles, 512, 0, stream>>>(src, dst, E, bcnt, gcur, thist, bptr, binned);
    k_deg<<<NB, B, 0, stream>>>(bptr, binned, dis, n);
    k_xw1<<<(n + 1 + B - 1) / B, B, 0, stream>>>(x, W1, dis, featp, n);
    k_agg<1><<<NB, 512, 0, stream>>>(bptr, binned, dis, featp, nullptr, b1, (void*)h1p, n);
    k_agg<2><<<NB, 512, 0, stream>>>(bptr, binned, dis, h1p, W2, b2, d_out, n);
}

// Round 7
// 214.891 us; speedup vs baseline: 2.6259x; 1.0705x over previous
//
#include <hip/hip_runtime.h>
#include <hip/hip_fp16.h>

// QNetGNN: 2-layer GCN, N=100000, E=3.2M, F: 128 -> 16 -> 32.
// R17: fusion + widening pass on the R16 pipeline (230.0us, all kernels
// below the 40us profile cutoff). Changes:
//  - k_deg FUSED into k_xw1 (k_deg_xw1, grid=NB): phase1 computes the
//    bucket's cnt->dis block-locally, phase2 does xw1 for the bucket's own
//    196 nodes (xw1 row r only needs dis[r] -> no grid dependency).
//    One dispatch + gap deleted. Dummy featp row n deleted (unread).
//  - W1 read DIRECT from global with uniform indices (scalar-cached s_load)
//    instead of LDS staging: removes 512 ds_read_b128/thread + a barrier.
//  - k_agg feature gathers widened: lane-PAIR x uint4 (1 VMEM req per edge
//    half-row instead of 2x uint2): halves gather instruction count.
//    Fixed-point int accumulation -> bit-exact under reordering.
//  - int4-vectorized edge reads in k_coarse + k_bin sort loop (scalar
//    fallback if E%4 != 0).
// Front-end structure (NB=511/BUCK=196 magic division, shfl scans, fused
// bcnt scan, fixed-point 2^18 LDS accumulation, fused W2) from R15/R16.

#define NNODES 100000
#define FIN    128
#define FHID   16
#define NACT   32
#define BUCK   196          // nodes per bucket (511 blocks ~= 2/CU balance)
#define NB     511          // ceil(100000/196)
#define MAGIC  21913099u    // ceil(2^32/196); exact for d < 39.7M (R12-verified)
#define TILE   4096
#define ASTRIDE 17          // LDS accumulator row stride (odd -> bank spread)
#define SCALE    262144.0f             // 2^18 fixed-point scale
#define INVSCALE 3.814697265625e-06f   // 2^-18

__device__ __forceinline__ int bucket_of(int d) {
    return (int)__umulhi((unsigned)d, MAGIC);
}

__device__ __forceinline__ unsigned pack2(float a, float b) {
    __half2 h = __floats2half2_rn(a, b);
    return *reinterpret_cast<unsigned*>(&h);
}

__device__ __forceinline__ float2 h2f(unsigned u) {
    return __half22float2(*reinterpret_cast<__half2*>(&u));
}

__device__ __forceinline__ int wave_iscan(int v, int lane) {
#pragma unroll
    for (int d = 1; d < 64; d <<= 1) {
        int u = __shfl_up(v, d, 64);
        if (lane >= d) v += u;
    }
    return v;
}

// ---- coarse histogram of dst buckets; also store per-tile hist (ushort) ----
__global__ void k_coarse(const int* __restrict__ dst, int E, int* __restrict__ bcnt,
                         unsigned short* __restrict__ thist) {
    __shared__ int hist[NB];
    int t = threadIdx.x;
    int tb = blockIdx.x * TILE;
    int tn = min(TILE, E - tb);
    for (int i = t; i < NB; i += 256) hist[i] = 0;
    __syncthreads();
    if ((E & 3) == 0) {                       // 16B-aligned tiles
        const int4* d4 = (const int4*)(dst + tb);
        int tn4 = tn >> 2;
        for (int i = t; i < tn4; i += 256) {
            int4 v = d4[i];
            atomicAdd(&hist[bucket_of(v.x)], 1);
            atomicAdd(&hist[bucket_of(v.y)], 1);
            atomicAdd(&hist[bucket_of(v.z)], 1);
            atomicAdd(&hist[bucket_of(v.w)], 1);
        }
        for (int i = (tn4 << 2) + t; i < tn; i += 256)
            atomicAdd(&hist[bucket_of(dst[tb + i])], 1);
    } else {
        for (int i = t; i < tn; i += 256)
            atomicAdd(&hist[bucket_of(dst[tb + i])], 1);
    }
    __syncthreads();
    size_t row = (size_t)blockIdx.x * NB;
    for (int i = t; i < NB; i += 256) {
        int hv = hist[i];
        thist[row + i] = (unsigned short)hv;
        if (hv) atomicAdd(&bcnt[i], hv);
    }
}

// ---- bin: staged LDS counting sort; shfl scans; bcnt scan folded in ----
__global__ void __launch_bounds__(512) k_bin(
        const int* __restrict__ src, const int* __restrict__ dst, int E,
        const int* __restrict__ bcnt, int* __restrict__ gcur,
        const unsigned short* __restrict__ thist,
        int* __restrict__ bptr, unsigned* __restrict__ binned) {
    __shared__ unsigned staged[TILE];     // 16 KB
    __shared__ int gscat[TILE];           // 16 KB
    __shared__ int lcur[NB];
    __shared__ int dbase[NB];
    __shared__ int bptrS[NB];
    __shared__ int wsum[8];
    int t = threadIdx.x, lane = t & 63, wv = t >> 6;

    // --- block-wide exclusive scan of bcnt -> bptrS (shfl, 1 barrier) ---
    int c0 = (t < NB) ? bcnt[t] : 0;
    int incl0 = wave_iscan(c0, lane);
    if (lane == 63) wsum[wv] = incl0;
    __syncthreads();
    int add0 = 0;
#pragma unroll
    for (int i = 0; i < 8; ++i) add0 += (i < wv) ? wsum[i] : 0;
    incl0 += add0;
    int excl0 = incl0 - c0;
    if (t < NB) bptrS[t] = excl0;
    if (blockIdx.x == 0) {                // publish bptr for k_deg_xw1/k_agg
        if (t < NB) bptr[t] = excl0;
        if (t == NB) bptr[NB] = excl0;    // t==NB: c0=0 -> excl0 = total E
    }
    __syncthreads();                      // wsum reuse + bptrS visibility

    // --- per-tile local scan of thist row (shfl, 1 barrier) ---
    int tb = blockIdx.x * TILE;
    int tn = min(TILE, E - tb);
    size_t row = (size_t)blockIdx.x * NB;
    int c = (t < NB) ? (int)thist[row + t] : 0;
    int incl = wave_iscan(c, lane);
    if (lane == 63) wsum[wv] = incl;
    __syncthreads();
    int add = 0;
#pragma unroll
    for (int i = 0; i < 8; ++i) add += (i < wv) ? wsum[i] : 0;
    incl += add;
    int excl = incl - c;                  // tile-local bucket start
    if (t < NB) {
        lcur[t] = excl;
        int gb = (c > 0) ? atomicAdd(&gcur[t], c) : 0;   // zero-based cursor
        dbase[t] = bptrS[t] + gb - excl;  // dest = dbase[b] + staged pos
    }
    __syncthreads();

    if ((E & 3) == 0) {
        const int4* d4 = (const int4*)(dst + tb);
        const int4* s4 = (const int4*)(src + tb);
        int tn4 = tn >> 2;
        for (int i = t; i < tn4; i += 512) {
            int4 dv = d4[i], sv = s4[i];
#pragma unroll
            for (int j = 0; j < 4; ++j) {
                int d = (j == 0) ? dv.x : (j == 1) ? dv.y : (j == 2) ? dv.z : dv.w;
                int s = (j == 0) ? sv.x : (j == 1) ? sv.y : (j == 2) ? sv.z : sv.w;
                int b = bucket_of(d);
                int pos = atomicAdd(&lcur[b], 1);
                staged[pos] = ((unsigned)s << 8) | (unsigned)(d - b * BUCK);
                gscat[pos] = dbase[b] + pos;
            }
        }
        for (int i = (tn4 << 2) + t; i < tn; i += 512) {
            int d = dst[tb + i], s = src[tb + i];
            int b = bucket_of(d);
            int pos = atomicAdd(&lcur[b], 1);
            staged[pos] = ((unsigned)s << 8) | (unsigned)(d - b * BUCK);
            gscat[pos] = dbase[b] + pos;
        }
    } else {
        for (int i = t; i < tn; i += 512) {
            int d = dst[tb + i], s = src[tb + i];
            int b = bucket_of(d);
            int pos = atomicAdd(&lcur[b], 1);
            staged[pos] = ((unsigned)s << 8) | (unsigned)(d - b * BUCK);
            gscat[pos] = dbase[b] + pos;
        }
    }
    __syncthreads();
    for (int j = t; j < tn; j += 512) binned[gscat[j]] = staged[j];
}

#define FMA4(A, S, W) { (A).x += (S) * (W).x; (A).y += (S) * (W).y; \
                        (A).z += (S) * (W).z; (A).w += (S) * (W).w; }

// ---- fused: per-bucket degrees -> dis, then xw1 for the bucket's nodes ----
// featp = fp16((x @ W1) * dis). W1 read direct from global (uniform index
// -> scalar loads, 8KB scalar-cache resident).
__global__ void __launch_bounds__(256) k_deg_xw1(
        const int* __restrict__ bptr, const unsigned* __restrict__ binned,
        const float* __restrict__ x, const float* __restrict__ W1,
        float* __restrict__ dis, __half* __restrict__ featp, int n) {
    __shared__ int cnt[BUCK];
    __shared__ float sdis[BUCK];
    int t = threadIdx.x;
    int bk = blockIdx.x;
    if (t < BUCK) cnt[t] = 0;
    __syncthreads();
    int beg = bptr[bk], end = bptr[bk + 1];
    for (int i = beg + t; i < end; i += 256) atomicAdd(&cnt[binned[i] & 255], 1);
    __syncthreads();
    int node = bk * BUCK + t;
    if (t < BUCK) {
        float dv = rsqrtf((float)cnt[t] + 1.0f);
        sdis[t] = dv;
        if (node < n) dis[node] = dv;
    }
    __syncthreads();
    if (t >= BUCK || node >= n) return;

    const float4* xr = (const float4*)(x + (size_t)node * FIN);
    const float4* w4 = (const float4*)W1;     // [128][4] float4s, uniform idx
    float4 a0 = make_float4(0.f, 0.f, 0.f, 0.f), a1 = a0, a2 = a0, a3 = a0;
#pragma unroll 8
    for (int k4 = 0; k4 < FIN / 4; ++k4) {
        float4 xv = xr[k4];
        int kb = k4 * 16;
        FMA4(a0, xv.x, w4[kb + 0]);  FMA4(a1, xv.x, w4[kb + 1]);
        FMA4(a2, xv.x, w4[kb + 2]);  FMA4(a3, xv.x, w4[kb + 3]);
        FMA4(a0, xv.y, w4[kb + 4]);  FMA4(a1, xv.y, w4[kb + 5]);
        FMA4(a2, xv.y, w4[kb + 6]);  FMA4(a3, xv.y, w4[kb + 7]);
        FMA4(a0, xv.z, w4[kb + 8]);  FMA4(a1, xv.z, w4[kb + 9]);
        FMA4(a2, xv.z, w4[kb + 10]); FMA4(a3, xv.z, w4[kb + 11]);
        FMA4(a0, xv.w, w4[kb + 12]); FMA4(a1, xv.w, w4[kb + 13]);
        FMA4(a2, xv.w, w4[kb + 14]); FMA4(a3, xv.w, w4[kb + 15]);
    }
    float d = sdis[t];
    uint4 w0, w1;
    w0.x = pack2(a0.x * d, a0.y * d); w0.y = pack2(a0.z * d, a0.w * d);
    w0.z = pack2(a1.x * d, a1.y * d); w0.w = pack2(a1.z * d, a1.w * d);
    w1.x = pack2(a2.x * d, a2.y * d); w1.y = pack2(a2.z * d, a2.w * d);
    w1.z = pack2(a3.x * d, a3.y * d); w1.w = pack2(a3.z * d, a3.w * d);
    uint4* hr = (uint4*)(featp + (size_t)node * FHID);   // 32 B row
    hr[0] = w0; hr[1] = w1;
}

// add 8 fp16 (one uint4 = 16B half-row) into acc at dptr as fixed-point
#define ADD8(U, dptr) { \
    float2 f0_ = h2f((U).x), f1_ = h2f((U).y), f2_ = h2f((U).z), f3_ = h2f((U).w); \
    atomicAdd(&(dptr)[0], __float2int_rn(f0_.x * SCALE)); \
    atomicAdd(&(dptr)[1], __float2int_rn(f0_.y * SCALE)); \
    atomicAdd(&(dptr)[2], __float2int_rn(f1_.x * SCALE)); \
    atomicAdd(&(dptr)[3], __float2int_rn(f1_.y * SCALE)); \
    atomicAdd(&(dptr)[4], __float2int_rn(f2_.x * SCALE)); \
    atomicAdd(&(dptr)[5], __float2int_rn(f2_.y * SCALE)); \
    atomicAdd(&(dptr)[6], __float2int_rn(f3_.x * SCALE)); \
    atomicAdd(&(dptr)[7], __float2int_rn(f3_.y * SCALE)); }

// ---- push aggregation: block per bucket, int32 fixed-point LDS acc ----
// Lane PAIRS per edge: p2 = t&1 selects the 16B half-row (uint4 gather,
// 1 VMEM request per lane), 8 ds_add each. 2 edges in flight per pair.
// L==1: h1p = fp16(relu(di*acc + b1)*di)   [N,16]
// L==2: out = (di*acc) @ W2 + b2           [N,32] fp32 (W2 fused)
template <int L>
__global__ void __launch_bounds__(512) k_agg(
        const int* __restrict__ bptr, const unsigned* __restrict__ binned,
        const float* __restrict__ dis, const __half* __restrict__ featp,
        const float* __restrict__ W2, const float* __restrict__ bias,
        void* __restrict__ outp, int n) {
    __shared__ int acc[BUCK * ASTRIDE];      // 13.3 KB
    __shared__ float wb[FHID * NACT];
    __shared__ float bs[NACT];
    int t = threadIdx.x;
    int bk = blockIdx.x;
    int base = bk * BUCK;
    int nn = min(BUCK, n - base);
    const uint4* fp4 = (const uint4*)featp;  // 2 uint4 (16B halves) per row
    if (L == 2) {
        for (int i = t; i < FHID * NACT; i += 512) wb[i] = W2[i];
        if (t < NACT) bs[t] = bias[t];
    }
    // init acc with the self-loop row (featp pre-scaled by dis[node])
    for (int idx = t; idx < BUCK * 2; idx += 512) {
        int d = idx >> 1, p2 = idx & 1;
        int* a = &acc[d * ASTRIDE + p2 * 8];
        if (d < nn) {
            uint4 u = fp4[(size_t)((base + d) << 1) + p2];
            float2 f0 = h2f(u.x), f1 = h2f(u.y), f2 = h2f(u.z), f3 = h2f(u.w);
            a[0] = __float2int_rn(f0.x * SCALE);
            a[1] = __float2int_rn(f0.y * SCALE);
            a[2] = __float2int_rn(f1.x * SCALE);
            a[3] = __float2int_rn(f1.y * SCALE);
            a[4] = __float2int_rn(f2.x * SCALE);
            a[5] = __float2int_rn(f2.y * SCALE);
            a[6] = __float2int_rn(f3.x * SCALE);
            a[7] = __float2int_rn(f3.y * SCALE);
        } else {
            a[0] = 0; a[1] = 0; a[2] = 0; a[3] = 0;
            a[4] = 0; a[5] = 0; a[6] = 0; a[7] = 0;
        }
    }
    __syncthreads();
    int beg = bptr[bk], end = bptr[bk + 1];
    int pr = t >> 1, p2 = t & 1;             // lane pair per edge
    int i = beg + pr;
    for (; i + 256 < end; i += 512) {        // 2 edges in flight per pair
        unsigned e0 = binned[i];
        unsigned e1 = binned[i + 256];
        uint4 u0 = fp4[(size_t)((e0 >> 8) << 1) + p2];
        uint4 u1 = fp4[(size_t)((e1 >> 8) << 1) + p2];
        int* d0 = &acc[(int)(e0 & 255) * ASTRIDE + p2 * 8];
        ADD8(u0, d0);
        int* d1 = &acc[(int)(e1 & 255) * ASTRIDE + p2 * 8];
        ADD8(u1, d1);
    }
    if (i < end) {
        unsigned e0 = binned[i];
        uint4 u0 = fp4[(size_t)((e0 >> 8) << 1) + p2];
        int* d0 = &acc[(int)(e0 & 255) * ASTRIDE + p2 * 8];
        ADD8(u0, d0);
    }
    __syncthreads();
    if (L == 1) {
        for (int idx = t; idx < nn * 4; idx += 512) {
            int d = idx >> 2, pp = idx & 3;
            int node = base + d;
            float di = dis[node];
            const int* a = &acc[d * ASTRIDE + pp * 4];
            float4 bv = ((const float4*)bias)[pp];
            float f0 = (float)a[0] * INVSCALE;
            float f1 = (float)a[1] * INVSCALE;
            float f2 = (float)a[2] * INVSCALE;
            float f3 = (float)a[3] * INVSCALE;
            float rx = fmaxf(di * f0 + bv.x, 0.f) * di;   // pre-scaled for layer 2
            float ry = fmaxf(di * f1 + bv.y, 0.f) * di;
            float rz = fmaxf(di * f2 + bv.z, 0.f) * di;
            float rw = fmaxf(di * f3 + bv.w, 0.f) * di;
            uint2 w;
            w.x = pack2(rx, ry);
            w.y = pack2(rz, rw);
            ((uint2*)outp)[(size_t)node * 4 + pp] = w;
        }
    } else {
        for (int idx = t; idx < nn * 2; idx += 512) {
            int d = idx >> 1, h = idx & 1;   // 2 threads/node, 16 cols each
            int node = base + d;
            float di = dis[node];
            float p16[FHID];
#pragma unroll
            for (int c = 0; c < FHID; ++c)
                p16[c] = di * ((float)acc[d * ASTRIDE + c] * INVSCALE);
            float o[16];
#pragma unroll
            for (int j = 0; j < 16; ++j) {
                int col = h * 16 + j;
                float s = bs[col];
#pragma unroll
                for (int c = 0; c < FHID; ++c) s += p16[c] * wb[c * NACT + col];
                o[j] = s;
            }
            float4* orow = (float4*)outp + (size_t)node * 8 + h * 4;
            orow[0] = make_float4(o[0], o[1], o[2], o[3]);
            orow[1] = make_float4(o[4], o[5], o[6], o[7]);
            orow[2] = make_float4(o[8], o[9], o[10], o[11]);
            orow[3] = make_float4(o[12], o[13], o[14], o[15]);
        }
    }
}

extern "C" void kernel_launch(void* const* d_in, const int* in_sizes, int n_in,
                              void* d_out, int out_size, void* d_ws, size_t ws_size,
                              hipStream_t stream) {
    const float* x  = (const float*)d_in[0];
    const float* W1 = (const float*)d_in[1];
    const float* b1 = (const float*)d_in[2];
    const float* W2 = (const float*)d_in[3];
    const float* b2 = (const float*)d_in[4];
    const int*   ei = (const int*)d_in[5];
    const int E = in_sizes[5] / 2;
    const int n = NNODES;
    const int npad = n + 8;               // keeps fp16 tables 16B-aligned
    const int* src = ei;
    const int* dst = ei + E;
    const int ntiles = (E + TILE - 1) / TILE;

    // floats: dis[n] | featp fp16 [16*npad] | h1p fp16 [16*npad]
    // ints:   bcnt[NB] gcur[NB] bptr[NB+1] | thist[ntiles*NB] ushort | binned[E]
    float* fb    = (float*)d_ws;
    float* dis   = fb;
    __half* featp = (__half*)(fb + (size_t)n);
    __half* h1p   = featp + (size_t)16 * npad;
    int*   ib    = (int*)(h1p + (size_t)16 * npad);
    int*   bcnt  = ib;
    int*   gcur  = ib + NB;
    int*   bptr  = ib + 2 * NB;
    size_t thist_off = (size_t)(3 * NB + 1);
    unsigned short* thist = (unsigned short*)(ib + thist_off);
    size_t thist_ints = ((size_t)ntiles * NB + 1) / 2;
    unsigned* binned = (unsigned*)(ib + thist_off + thist_ints);

    (void)hipMemsetAsync(bcnt, 0, 2 * NB * sizeof(int), stream);   // bcnt + gcur

    const int B = 256;
    k_coarse<<<ntiles, B, 0, stream>>>(dst, E, bcnt, thist);
    k_bin<<<ntiles, 512, 0, stream>>>(src, dst, E, bcnt, gcur, thist, bptr, binned);
    k_deg_xw1<<<NB, B, 0, stream>>>(bptr, binned, x, W1, dis, featp, n);
    k_agg<1><<<NB, 512, 0, stream>>>(bptr, binned, dis, featp, nullptr, b1, (void*)h1p, n);
    k_agg<2><<<NB, 512, 0, stream>>>(bptr, binned, dis, h1p, W2, b2, d_out, n);
}